// Round 6
// baseline (2252.869 us; speedup 1.0000x reference)
//
#include <hip/hip_runtime.h>

// LTC RNN (LiquidNeuralNetwork): B=512, S=512, H=128, 2 layers, RK4.
// Round 6: round-4 structure + __launch_bounds__(1024, 4).
// Round 5's counters showed the compiler capped VGPRs at 64 (8 waves/SIMD
// occupancy target) and spilled the entire weight-fragment set to scratch
// (WRITE_SIZE 2 KB -> 1541 KB). The (1024, 4) bound sets the budget to
// 512/4 = 128 VGPRs: weights (64) + state (~50) fit, spills vanish, and the
// 4-waves/SIMD latency-hiding experiment actually runs.
// Structure: 32 blocks x 1024 threads (16 waves). Waves 0-7 = layer 0 at step
// t; waves 8-15 = layer 1 at step t-1 (lag-1 pipeline; h1 never feeds h0).
// Each wave owns 1 gate-tile + 1 rec-tile (rows 16wl..16wl+15): 8 MFMA +
// 4 gate-evals/lane per slot. Numerics identical to rounds 1-5.

typedef _Float16 f16;
typedef _Float16 f16x4 __attribute__((ext_vector_type(4)));
typedef _Float16 f16x8 __attribute__((ext_vector_type(8)));
typedef float f32x4 __attribute__((ext_vector_type(4)));

#define NSTEP 512
#define OFF_A0 0
#define OFF_A1 32768
#define OFF_AIO 65536
#define OFF_AX 98304
#define W_TOTAL 122880

// LDS byte offsets. hh buffers: [16 cols][136 f16] = 4352 B each.
#define HQ0 0
#define HQ1 4352
#define L0A 8704
#define L0B 13056
#define L1A 17408
#define L1B 21760
#define L1H 26112
#define XT 30464

__device__ __forceinline__ float rcp_f(float x) { return __builtin_amdgcn_rcpf(x); }
__device__ __forceinline__ float tanh_f(float x) {
  float e = __expf(2.f * x);
  return 1.f - 2.f * rcp_f(e + 1.f);
}
// sigmoid(t) for t in [-1,1] (t = tanh(...)): odd Taylor of 0.5+0.5*tanh(t/2), |err|<3e-6
__device__ __forceinline__ float sig_poly(float t) {
  float s = t * t;
  float p = fmaf(s, 2.1356861e-5f, -2.1081349e-4f);
  p = fmaf(s, p, 2.0833333e-3f);
  p = fmaf(s, p, -2.0833333e-2f);
  p = fmaf(s, p, 0.25f);
  return fmaf(t, p, 0.5f);
}

// Pack all recurrent-loop weights into f16 MFMA A-fragments.
// A-frag (16x16x32): A[m=lane&15][k=(lane>>4)*8+j], row-tile T = rows 16T..16T+15.
// A0 @0      [T8][sel2][kc4][lane64][j8]  sel0=Wg0 h-part, sel1=Wrec0
// A1 @32768  same                          sel0=Wg1 h-part, sel1=Wrec1
// AIO@65536  same                          sel0=Win1,       sel1=Wg1 x-part
// AX @98304  [T8][sel2][kc3][lane64][j8]  sel0=Win0,       sel1=Wg0 x-part (K=96)
__global__ __launch_bounds__(256) void prep_kernel(
    const float* __restrict__ Win0, const float* __restrict__ Wrec0,
    const float* __restrict__ Wg0, const float* __restrict__ Win1,
    const float* __restrict__ Wrec1, const float* __restrict__ Wg1,
    f16* __restrict__ W) {
  int i = blockIdx.x * 256 + threadIdx.x;
  if (i >= W_TOTAL) return;
  if (i < OFF_AX) {
    int sec = i >> 15;
    int r = i & 32767;
    int j = r & 7, lane = (r >> 3) & 63, kc = (r >> 9) & 3, sel = (r >> 11) & 1,
        w = (r >> 12) & 7;
    int row = w * 16 + (lane & 15);
    int k = kc * 32 + ((lane >> 4) << 3) + j;
    float v;
    if (sec == 0)
      v = sel ? Wrec0[row * 128 + k] : Wg0[row * 224 + 96 + k];
    else if (sec == 1)
      v = sel ? Wrec1[row * 128 + k] : Wg1[row * 256 + 128 + k];
    else
      v = sel ? Wg1[row * 256 + k] : Win1[row * 128 + k];
    W[i] = (f16)v;
  } else {
    int r = i - OFF_AX;
    int j = r & 7, lane = (r >> 3) & 63, g = r >> 9;
    int kc = g % 3, sg = g / 3;
    int sel = sg & 1, w = sg >> 1;
    int row = w * 16 + (lane & 15);
    int k = kc * 32 + ((lane >> 4) << 3) + j;
    W[i] = (f16)(sel ? Wg0[row * 224 + k] : Win0[row * 96 + k]);
  }
}

#define MFMA16(A, B, C) __builtin_amdgcn_mfma_f32_16x16x32_f16((A), (B), (C), 0, 0, 0)
#define ZERO4 ((f32x4){0.f, 0.f, 0.f, 0.f})

// 1-tile-pair matvec accumulate: ga/ra += {awg,awr} * B-frag(SRC).
#define MM2(SRC)                                                    \
  {                                                                 \
    const f16* bp_ = (SRC) + c * 136 + 8 * q;                       \
    _Pragma("unroll") for (int kc_ = 0; kc_ < 4; ++kc_) {           \
      f16x8 bf_ = *(const f16x8*)(bp_ + kc_ * 32);                  \
      ga = MFMA16(awg[kc_], bf_, ga);                               \
      ra = MFMA16(awr[kc_], bf_, ra);                               \
    }                                                               \
  }

// io projection with the au/ag2 fragment set (KCN k-chunks) into ga/ra.
#define MMIO(SRC, KCN)                                              \
  {                                                                 \
    const f16* bp_ = (SRC) + c * 136 + 8 * q;                       \
    _Pragma("unroll") for (int kc_ = 0; kc_ < (KCN); ++kc_) {       \
      f16x8 bf_ = *(const f16x8*)(bp_ + kc_ * 32);                  \
      ga = MFMA16(au[kc_], bf_, ga);                                \
      ra = MFMA16(ag2[kc_], bf_, ra);                               \
    }                                                               \
  }

// RK stage body: gate math on 4 (gate,rec) pairs, ksum += WC*k, eval point
// hhc = h + HC*k, write f16 eval point to DST.
#define GATEALL(WC, HC, DST)                                        \
  {                                                                 \
    f16x4 hv_;                                                      \
    _Pragma("unroll") for (int r_ = 0; r_ < 4; ++r_) {              \
      float th_ = tanh_f(ga[r_] + gx[r_]);                          \
      float gt_ = sig_poly(th_);                                    \
      float kk_ = fmaf(gt_, ra[r_], fmaf(-itv[r_], hhc[r_], u[r_]));\
      ksum[r_] = fmaf((WC), kk_, ksum[r_]);                         \
      float hn_ = fmaf((HC), kk_, hst[r_]);                         \
      hhc[r_] = hn_;                                                \
      hv_[r_] = (f16)hn_;                                           \
    }                                                               \
    *(f16x4*)((DST) + c * 136 + jb) = hv_;                          \
  }

// RK stage 4: h_new = tanh(h + ksum/6), becomes both state and next stage-1 eval.
#define GATEFIN(DST)                                                \
  {                                                                 \
    f16x4 hv_;                                                      \
    _Pragma("unroll") for (int r_ = 0; r_ < 4; ++r_) {              \
      float th_ = tanh_f(ga[r_] + gx[r_]);                          \
      float gt_ = sig_poly(th_);                                    \
      float kk_ = fmaf(gt_, ra[r_], fmaf(-itv[r_], hhc[r_], u[r_]));\
      float ks_ = ksum[r_] + kk_;                                   \
      float hn_ = tanh_f(fmaf(ks_, 0.16666667f, hst[r_]));          \
      hst[r_] = hn_;                                                \
      hhc[r_] = hn_;                                                \
      hv_[r_] = (f16)hn_;                                           \
    }                                                               \
    *(f16x4*)((DST) + c * 136 + jb) = hv_;                          \
  }

#define ZACC { ga = ZERO4; ra = ZERO4; }

__global__ __launch_bounds__(1024, 4) void ltc_kernel(
    const float* __restrict__ seq, const float* __restrict__ ctx,
    const float* __restrict__ tau0p, const float* __restrict__ bg0p,
    const float* __restrict__ tau1p, const float* __restrict__ bg1p,
    const float* __restrict__ W1, const float* __restrict__ b1,
    const float* __restrict__ W2, const float* __restrict__ b2,
    const f16* __restrict__ W, float* __restrict__ out) {
  __shared__ __align__(16) char smem[32768];
  f16* hq0 = (f16*)(smem + HQ0);
  f16* hq1 = (f16*)(smem + HQ1);
  f16* l0a = (f16*)(smem + L0A);
  f16* l0b = (f16*)(smem + L0B);
  f16* l1a = (f16*)(smem + L1A);
  f16* l1b = (f16*)(smem + L1B);
  f16* l1h = (f16*)(smem + L1H);
  f16* xt = (f16*)(smem + XT);

  const int tid = threadIdx.x;
  const int w16 = tid >> 6, lane = tid & 63;
  const int q = lane >> 4, c = lane & 15;
  const int wl = w16 & 7;             // tile index within layer group
  const bool isL0 = (w16 < 8);
  const int bg = blockIdx.x;
  const int jb = 16 * wl + 4 * q;     // this lane's 4 owned h-rows

  f16* bufA = isL0 ? l0a : l1a;
  f16* bufB = isL0 ? l0b : l1b;

  // ---- weight fragments -> VGPRs (held for whole kernel) ----
  // awg/awr: recurrent gate-h / rec tile (T=wl). au/ag2: L0 -> (Win0, Wg0x)
  // K=96 (2 chunks + ctx); L1 -> (Win1, Wg1x) K=128 (4 chunks).
  f16x8 awg[4], awr[4], au[4], ag2[4];
  f16x8 bctx;
  if (isL0) {
#pragma unroll
    for (int kc = 0; kc < 4; ++kc) {
      awg[kc] = *(const f16x8*)(W + OFF_A0 + (((wl * 2 + 0) * 4 + kc) * 64 + lane) * 8);
      awr[kc] = *(const f16x8*)(W + OFF_A0 + (((wl * 2 + 1) * 4 + kc) * 64 + lane) * 8);
    }
#pragma unroll
    for (int kc = 0; kc < 3; ++kc) {
      au[kc] = *(const f16x8*)(W + OFF_AX + (((wl * 2 + 0) * 3 + kc) * 64 + lane) * 8);
      ag2[kc] = *(const f16x8*)(W + OFF_AX + (((wl * 2 + 1) * 3 + kc) * 64 + lane) * 8);
    }
    au[3] = (f16x8)(f16)0.f;
    ag2[3] = (f16x8)(f16)0.f;
    const float* cp = ctx + (bg * 16 + c) * 32 + 8 * q;
#pragma unroll
    for (int j = 0; j < 8; ++j) bctx[j] = (f16)cp[j];
  } else {
#pragma unroll
    for (int kc = 0; kc < 4; ++kc) {
      awg[kc] = *(const f16x8*)(W + OFF_A1 + (((wl * 2 + 0) * 4 + kc) * 64 + lane) * 8);
      awr[kc] = *(const f16x8*)(W + OFF_A1 + (((wl * 2 + 1) * 4 + kc) * 64 + lane) * 8);
      au[kc] = *(const f16x8*)(W + OFF_AIO + (((wl * 2 + 0) * 4 + kc) * 64 + lane) * 8);
      ag2[kc] = *(const f16x8*)(W + OFF_AIO + (((wl * 2 + 1) * 4 + kc) * 64 + lane) * 8);
    }
  }

  // per-lane params for the 4 owned rows
  const float* taup = isL0 ? tau0p : tau1p;
  const float* bgp = isL0 ? bg0p : bg1p;
  f32x4 itv, bgv;
#pragma unroll
  for (int r = 0; r < 4; ++r) {
    float t = taup[jb + r];
    itv[r] = 1.f / (logf(1.f + __expf(t)) + 1.f);  // 1/(softplus+1)
    bgv[r] = bgp[jb + r];
  }

  f32x4 hst = ZERO4, hhc = ZERO4, u = ZERO4, gx = ZERO4, ksum = ZERO4, ga, ra;

  // zero initial-state buffers: hq1 (h0 at t=-1) and l1h (h1 at t=-1)
  for (int j = tid; j < 2176; j += 1024) {
    hq1[j] = (f16)0.f;
    l1h[j] = (f16)0.f;
  }
  // pre-stage x(0): 256 threads (waves 0-3), float4 each
  const int bs = tid >> 4, fp = tid & 15;
  const size_t seqrow = ((size_t)(bg * 16 + (bs & 15))) * NSTEP * 64 + 4 * fp;
  if (tid < 256) {
    float4 sv = *(const float4*)(seq + seqrow);
    *(f16x4*)(xt + bs * 72 + 4 * fp) =
        (f16x4){(f16)sv.x, (f16)sv.y, (f16)sv.z, (f16)sv.w};
  }
  __syncthreads();

  float4 sqv = {0.f, 0.f, 0.f, 0.f};

#pragma unroll 1
  for (int i = 0; i <= NSTEP; ++i) {
    const f16* hprev = ((i + 1) & 1) ? hq1 : hq0;  // h0(t-1) buffer

    // ===== slot A: L0 x-proj + stage1 | L1 io-proj + stage1 =====
    if (isL0) {
      if (i < NSTEP) {
        if (tid < 256 && i + 1 < NSTEP)
          sqv = *(const float4*)(seq + seqrow + (size_t)(i + 1) * 64);
        ZACC;
        {  // x projection: u = Win0*x, gx = Wg0x*x (K=96: 2 chunks from xt + ctx)
          f16x8 bx0 = *(const f16x8*)(xt + c * 72 + 8 * q);
          f16x8 bx1 = *(const f16x8*)(xt + c * 72 + 32 + 8 * q);
          ga = MFMA16(au[0], bx0, ga);
          ra = MFMA16(ag2[0], bx0, ra);
          ga = MFMA16(au[1], bx1, ga);
          ra = MFMA16(ag2[1], bx1, ra);
          ga = MFMA16(au[2], bctx, ga);
          ra = MFMA16(ag2[2], bctx, ra);
        }
        u = ga;
#pragma unroll
        for (int r = 0; r < 4; ++r) gx[r] = ra[r] + bgv[r];
        ZACC;
        MM2(hprev);  // stage 1 on h0(t-1)
        ksum = ZERO4;
        GATEALL(1.0f, 0.5f, bufA);
      }
    } else {
      if (i >= 1) {
        ZACC;
        MMIO(hprev, 4);  // u1 = Win1*h0_new, g1x = Wg1x*h0_new
        u = ga;
#pragma unroll
        for (int r = 0; r < 4; ++r) gx[r] = ra[r] + bgv[r];
        ZACC;
        MM2(l1h);  // stage 1 on h1(t-2)
        ksum = ZERO4;
        GATEALL(1.0f, 0.5f, bufA);
      }
    }
    __syncthreads();

    // ===== slot B: stage 2 =====
    if ((isL0 && i < NSTEP) || (!isL0 && i >= 1)) {
      ZACC;
      MM2(bufA);
      GATEALL(2.0f, 0.5f, bufB);
    }
    __syncthreads();

    // ===== slot C: stage 3 =====
    if ((isL0 && i < NSTEP) || (!isL0 && i >= 1)) {
      ZACC;
      MM2(bufB);
      GATEALL(2.0f, 1.0f, bufA);
    }
    __syncthreads();

    // ===== slot D: stage 4 -> h_new; L0 stages x(i+1) =====
    if (isL0) {
      if (i < NSTEP) {
        ZACC;
        MM2(bufA);
        GATEFIN((i & 1) ? hq1 : hq0);
        if (tid < 256 && i + 1 < NSTEP)
          *(f16x4*)(xt + bs * 72 + 4 * fp) =
              (f16x4){(f16)sqv.x, (f16)sqv.y, (f16)sqv.z, (f16)sqv.w};
      }
    } else {
      if (i >= 1) {
        ZACC;
        MM2(bufA);
        GATEFIN(l1h);
      }
    }
    __syncthreads();
  }

  // ======================= classifier epilogue ===========================
  float* h1f = (float*)smem;  // [16][132] f32
  if (!isL0) *(f32x4*)(h1f + c * 132 + jb) = hst;
  __syncthreads();
  float* z1 = (float*)(smem + 16 * 132 * 4);  // [16][64] f32
  {
    int b = tid >> 6, o = tid & 63;  // 16 x 64 = 1024 threads exactly
    const float* wr = W1 + o * 128;
    const float* hr = h1f + b * 132;
    float s = 0.f;
#pragma unroll
    for (int j = 0; j < 128; j += 4) {
      f32x4 wv = *(const f32x4*)(wr + j);
      f32x4 hv = *(const f32x4*)(hr + j);
      s += wv[0] * hv[0] + wv[1] * hv[1] + wv[2] * hv[2] + wv[3] * hv[3];
    }
    s += b1[o];
    z1[b * 64 + o] = fmaxf(s, 0.f);
  }
  __syncthreads();
  if (tid < 16) {
    float s = b2[0];
#pragma unroll
    for (int o = 0; o < 64; ++o) s += z1[tid * 64 + o] * W2[o];
    out[bg * 16 + tid] = rcp_f(1.f + __expf(-s));
  }
}

extern "C" void kernel_launch(void* const* d_in, const int* in_sizes, int n_in,
                              void* d_out, int out_size, void* d_ws, size_t ws_size,
                              hipStream_t stream) {
  (void)in_sizes; (void)n_in; (void)out_size; (void)ws_size;
  const float* seq = (const float*)d_in[0];
  const float* ctx = (const float*)d_in[1];
  const float* tau0 = (const float*)d_in[2];
  const float* Win0 = (const float*)d_in[3];
  const float* Wrec0 = (const float*)d_in[4];
  const float* Wg0 = (const float*)d_in[5];
  const float* bg0 = (const float*)d_in[6];
  const float* tau1 = (const float*)d_in[7];
  const float* Win1 = (const float*)d_in[8];
  const float* Wrec1 = (const float*)d_in[9];
  const float* Wg1 = (const float*)d_in[10];
  const float* bg1 = (const float*)d_in[11];
  const float* W1 = (const float*)d_in[12];
  const float* b1 = (const float*)d_in[13];
  const float* W2 = (const float*)d_in[14];
  const float* b2 = (const float*)d_in[15];
  f16* W = (f16*)d_ws;  // 245760 B of packed fragments

  prep_kernel<<<480, 256, 0, stream>>>(Win0, Wrec0, Wg0, Win1, Wrec1, Wg1, W);
  ltc_kernel<<<32, 1024, 0, stream>>>(seq, ctx, tau0, bg0, tau1, bg1, W1, b1, W2,
                                      b2, W, (float*)d_out);
}

// Round 7
// 2239.652 us; speedup vs baseline: 1.0059x; 1.0059x over previous
//
#include <hip/hip_runtime.h>

// LTC RNN (LiquidNeuralNetwork): B=512, S=512, H=128, 2 layers, RK4.
// Round 7: round-4 structure, VGPR cap fixed via backend attributes.
// Rounds 5/6 showed __launch_bounds__(1024[,4]) leaves the allocator at a
// 64-VGPR / 8-waves-per-EU target -> entire weight-fragment set spilled
// (WRITE_SIZE 2 KB -> 1540 KB) and the latency-hiding experiment never ran.
// amdgpu_waves_per_eu(4,4) pins the occupancy target to exactly 4 waves/EU
// (16-wave block resident once per CU) -> 512/4 = 128 VGPR budget; weights
// (64) + state (~55) fit with no spills.
// Structure: 32 blocks x 1024 threads (16 waves). Waves 0-7 = layer 0 at step
// t; waves 8-15 = layer 1 at step t-1 (lag-1 pipeline; h1 never feeds h0).
// Each wave owns 1 gate-tile + 1 rec-tile (rows 16wl..16wl+15): 8 MFMA +
// 4 gate-evals/lane per slot. Numerics identical to rounds 1-6.

typedef _Float16 f16;
typedef _Float16 f16x4 __attribute__((ext_vector_type(4)));
typedef _Float16 f16x8 __attribute__((ext_vector_type(8)));
typedef float f32x4 __attribute__((ext_vector_type(4)));

#define NSTEP 512
#define OFF_A0 0
#define OFF_A1 32768
#define OFF_AIO 65536
#define OFF_AX 98304
#define W_TOTAL 122880

// LDS byte offsets. hh buffers: [16 cols][136 f16] = 4352 B each.
#define HQ0 0
#define HQ1 4352
#define L0A 8704
#define L0B 13056
#define L1A 17408
#define L1B 21760
#define L1H 26112
#define XT 30464

__device__ __forceinline__ float rcp_f(float x) { return __builtin_amdgcn_rcpf(x); }
__device__ __forceinline__ float tanh_f(float x) {
  float e = __expf(2.f * x);
  return 1.f - 2.f * rcp_f(e + 1.f);
}
// sigmoid(t) for t in [-1,1] (t = tanh(...)): odd Taylor of 0.5+0.5*tanh(t/2), |err|<3e-6
__device__ __forceinline__ float sig_poly(float t) {
  float s = t * t;
  float p = fmaf(s, 2.1356861e-5f, -2.1081349e-4f);
  p = fmaf(s, p, 2.0833333e-3f);
  p = fmaf(s, p, -2.0833333e-2f);
  p = fmaf(s, p, 0.25f);
  return fmaf(t, p, 0.5f);
}

// Pack all recurrent-loop weights into f16 MFMA A-fragments.
// A-frag (16x16x32): A[m=lane&15][k=(lane>>4)*8+j], row-tile T = rows 16T..16T+15.
// A0 @0      [T8][sel2][kc4][lane64][j8]  sel0=Wg0 h-part, sel1=Wrec0
// A1 @32768  same                          sel0=Wg1 h-part, sel1=Wrec1
// AIO@65536  same                          sel0=Win1,       sel1=Wg1 x-part
// AX @98304  [T8][sel2][kc3][lane64][j8]  sel0=Win0,       sel1=Wg0 x-part (K=96)
__global__ __launch_bounds__(256) void prep_kernel(
    const float* __restrict__ Win0, const float* __restrict__ Wrec0,
    const float* __restrict__ Wg0, const float* __restrict__ Win1,
    const float* __restrict__ Wrec1, const float* __restrict__ Wg1,
    f16* __restrict__ W) {
  int i = blockIdx.x * 256 + threadIdx.x;
  if (i >= W_TOTAL) return;
  if (i < OFF_AX) {
    int sec = i >> 15;
    int r = i & 32767;
    int j = r & 7, lane = (r >> 3) & 63, kc = (r >> 9) & 3, sel = (r >> 11) & 1,
        w = (r >> 12) & 7;
    int row = w * 16 + (lane & 15);
    int k = kc * 32 + ((lane >> 4) << 3) + j;
    float v;
    if (sec == 0)
      v = sel ? Wrec0[row * 128 + k] : Wg0[row * 224 + 96 + k];
    else if (sec == 1)
      v = sel ? Wrec1[row * 128 + k] : Wg1[row * 256 + 128 + k];
    else
      v = sel ? Wg1[row * 256 + k] : Win1[row * 128 + k];
    W[i] = (f16)v;
  } else {
    int r = i - OFF_AX;
    int j = r & 7, lane = (r >> 3) & 63, g = r >> 9;
    int kc = g % 3, sg = g / 3;
    int sel = sg & 1, w = sg >> 1;
    int row = w * 16 + (lane & 15);
    int k = kc * 32 + ((lane >> 4) << 3) + j;
    W[i] = (f16)(sel ? Wg0[row * 224 + k] : Win0[row * 96 + k]);
  }
}

#define MFMA16(A, B, C) __builtin_amdgcn_mfma_f32_16x16x32_f16((A), (B), (C), 0, 0, 0)
#define ZERO4 ((f32x4){0.f, 0.f, 0.f, 0.f})

// 1-tile-pair matvec accumulate: ga/ra += {awg,awr} * B-frag(SRC).
#define MM2(SRC)                                                    \
  {                                                                 \
    const f16* bp_ = (SRC) + c * 136 + 8 * q;                       \
    _Pragma("unroll") for (int kc_ = 0; kc_ < 4; ++kc_) {           \
      f16x8 bf_ = *(const f16x8*)(bp_ + kc_ * 32);                  \
      ga = MFMA16(awg[kc_], bf_, ga);                               \
      ra = MFMA16(awr[kc_], bf_, ra);                               \
    }                                                               \
  }

// io projection with the au/ag2 fragment set (KCN k-chunks) into ga/ra.
#define MMIO(SRC, KCN)                                              \
  {                                                                 \
    const f16* bp_ = (SRC) + c * 136 + 8 * q;                       \
    _Pragma("unroll") for (int kc_ = 0; kc_ < (KCN); ++kc_) {       \
      f16x8 bf_ = *(const f16x8*)(bp_ + kc_ * 32);                  \
      ga = MFMA16(au[kc_], bf_, ga);                                \
      ra = MFMA16(ag2[kc_], bf_, ra);                               \
    }                                                               \
  }

// RK stage body: gate math on 4 (gate,rec) pairs, ksum += WC*k, eval point
// hhc = h + HC*k, write f16 eval point to DST.
#define GATEALL(WC, HC, DST)                                        \
  {                                                                 \
    f16x4 hv_;                                                      \
    _Pragma("unroll") for (int r_ = 0; r_ < 4; ++r_) {              \
      float th_ = tanh_f(ga[r_] + gx[r_]);                          \
      float gt_ = sig_poly(th_);                                    \
      float kk_ = fmaf(gt_, ra[r_], fmaf(-itv[r_], hhc[r_], u[r_]));\
      ksum[r_] = fmaf((WC), kk_, ksum[r_]);                         \
      float hn_ = fmaf((HC), kk_, hst[r_]);                         \
      hhc[r_] = hn_;                                                \
      hv_[r_] = (f16)hn_;                                           \
    }                                                               \
    *(f16x4*)((DST) + c * 136 + jb) = hv_;                          \
  }

// RK stage 4: h_new = tanh(h + ksum/6), becomes both state and next stage-1 eval.
#define GATEFIN(DST)                                                \
  {                                                                 \
    f16x4 hv_;                                                      \
    _Pragma("unroll") for (int r_ = 0; r_ < 4; ++r_) {              \
      float th_ = tanh_f(ga[r_] + gx[r_]);                          \
      float gt_ = sig_poly(th_);                                    \
      float kk_ = fmaf(gt_, ra[r_], fmaf(-itv[r_], hhc[r_], u[r_]));\
      float ks_ = ksum[r_] + kk_;                                   \
      float hn_ = tanh_f(fmaf(ks_, 0.16666667f, hst[r_]));          \
      hst[r_] = hn_;                                                \
      hhc[r_] = hn_;                                                \
      hv_[r_] = (f16)hn_;                                           \
    }                                                               \
    *(f16x4*)((DST) + c * 136 + jb) = hv_;                          \
  }

#define ZACC { ga = ZERO4; ra = ZERO4; }

__global__ __attribute__((amdgpu_flat_work_group_size(1024, 1024)))
__attribute__((amdgpu_waves_per_eu(4, 4))) void ltc_kernel(
    const float* __restrict__ seq, const float* __restrict__ ctx,
    const float* __restrict__ tau0p, const float* __restrict__ bg0p,
    const float* __restrict__ tau1p, const float* __restrict__ bg1p,
    const float* __restrict__ W1, const float* __restrict__ b1,
    const float* __restrict__ W2, const float* __restrict__ b2,
    const f16* __restrict__ W, float* __restrict__ out) {
  __shared__ __align__(16) char smem[32768];
  f16* hq0 = (f16*)(smem + HQ0);
  f16* hq1 = (f16*)(smem + HQ1);
  f16* l0a = (f16*)(smem + L0A);
  f16* l0b = (f16*)(smem + L0B);
  f16* l1a = (f16*)(smem + L1A);
  f16* l1b = (f16*)(smem + L1B);
  f16* l1h = (f16*)(smem + L1H);
  f16* xt = (f16*)(smem + XT);

  const int tid = threadIdx.x;
  const int w16 = tid >> 6, lane = tid & 63;
  const int q = lane >> 4, c = lane & 15;
  const int wl = w16 & 7;             // tile index within layer group
  const bool isL0 = (w16 < 8);
  const int bg = blockIdx.x;
  const int jb = 16 * wl + 4 * q;     // this lane's 4 owned h-rows

  f16* bufA = isL0 ? l0a : l1a;
  f16* bufB = isL0 ? l0b : l1b;

  // ---- weight fragments -> VGPRs (held for whole kernel) ----
  // awg/awr: recurrent gate-h / rec tile (T=wl). au/ag2: L0 -> (Win0, Wg0x)
  // K=96 (2 chunks + ctx); L1 -> (Win1, Wg1x) K=128 (4 chunks).
  f16x8 awg[4], awr[4], au[4], ag2[4];
  f16x8 bctx;
  if (isL0) {
#pragma unroll
    for (int kc = 0; kc < 4; ++kc) {
      awg[kc] = *(const f16x8*)(W + OFF_A0 + (((wl * 2 + 0) * 4 + kc) * 64 + lane) * 8);
      awr[kc] = *(const f16x8*)(W + OFF_A0 + (((wl * 2 + 1) * 4 + kc) * 64 + lane) * 8);
    }
#pragma unroll
    for (int kc = 0; kc < 3; ++kc) {
      au[kc] = *(const f16x8*)(W + OFF_AX + (((wl * 2 + 0) * 3 + kc) * 64 + lane) * 8);
      ag2[kc] = *(const f16x8*)(W + OFF_AX + (((wl * 2 + 1) * 3 + kc) * 64 + lane) * 8);
    }
    au[3] = (f16x8)(f16)0.f;
    ag2[3] = (f16x8)(f16)0.f;
    const float* cp = ctx + (bg * 16 + c) * 32 + 8 * q;
#pragma unroll
    for (int j = 0; j < 8; ++j) bctx[j] = (f16)cp[j];
  } else {
#pragma unroll
    for (int kc = 0; kc < 4; ++kc) {
      awg[kc] = *(const f16x8*)(W + OFF_A1 + (((wl * 2 + 0) * 4 + kc) * 64 + lane) * 8);
      awr[kc] = *(const f16x8*)(W + OFF_A1 + (((wl * 2 + 1) * 4 + kc) * 64 + lane) * 8);
      au[kc] = *(const f16x8*)(W + OFF_AIO + (((wl * 2 + 0) * 4 + kc) * 64 + lane) * 8);
      ag2[kc] = *(const f16x8*)(W + OFF_AIO + (((wl * 2 + 1) * 4 + kc) * 64 + lane) * 8);
    }
  }

  // per-lane params for the 4 owned rows
  const float* taup = isL0 ? tau0p : tau1p;
  const float* bgp = isL0 ? bg0p : bg1p;
  f32x4 itv, bgv;
#pragma unroll
  for (int r = 0; r < 4; ++r) {
    float t = taup[jb + r];
    itv[r] = 1.f / (logf(1.f + __expf(t)) + 1.f);  // 1/(softplus+1)
    bgv[r] = bgp[jb + r];
  }

  f32x4 hst = ZERO4, hhc = ZERO4, u = ZERO4, gx = ZERO4, ksum = ZERO4, ga, ra;

  // zero initial-state buffers: hq1 (h0 at t=-1) and l1h (h1 at t=-1)
  for (int j = tid; j < 2176; j += 1024) {
    hq1[j] = (f16)0.f;
    l1h[j] = (f16)0.f;
  }
  // pre-stage x(0): 256 threads (waves 0-3), float4 each
  const int bs = tid >> 4, fp = tid & 15;
  const size_t seqrow = ((size_t)(bg * 16 + (bs & 15))) * NSTEP * 64 + 4 * fp;
  if (tid < 256) {
    float4 sv = *(const float4*)(seq + seqrow);
    *(f16x4*)(xt + bs * 72 + 4 * fp) =
        (f16x4){(f16)sv.x, (f16)sv.y, (f16)sv.z, (f16)sv.w};
  }
  __syncthreads();

  float4 sqv = {0.f, 0.f, 0.f, 0.f};

#pragma unroll 1
  for (int i = 0; i <= NSTEP; ++i) {
    const f16* hprev = ((i + 1) & 1) ? hq1 : hq0;  // h0(t-1) buffer

    // ===== slot A: L0 x-proj + stage1 | L1 io-proj + stage1 =====
    if (isL0) {
      if (i < NSTEP) {
        if (tid < 256 && i + 1 < NSTEP)
          sqv = *(const float4*)(seq + seqrow + (size_t)(i + 1) * 64);
        ZACC;
        {  // x projection: u = Win0*x, gx = Wg0x*x (K=96: 2 chunks from xt + ctx)
          f16x8 bx0 = *(const f16x8*)(xt + c * 72 + 8 * q);
          f16x8 bx1 = *(const f16x8*)(xt + c * 72 + 32 + 8 * q);
          ga = MFMA16(au[0], bx0, ga);
          ra = MFMA16(ag2[0], bx0, ra);
          ga = MFMA16(au[1], bx1, ga);
          ra = MFMA16(ag2[1], bx1, ra);
          ga = MFMA16(au[2], bctx, ga);
          ra = MFMA16(ag2[2], bctx, ra);
        }
        u = ga;
#pragma unroll
        for (int r = 0; r < 4; ++r) gx[r] = ra[r] + bgv[r];
        ZACC;
        MM2(hprev);  // stage 1 on h0(t-1)
        ksum = ZERO4;
        GATEALL(1.0f, 0.5f, bufA);
      }
    } else {
      if (i >= 1) {
        ZACC;
        MMIO(hprev, 4);  // u1 = Win1*h0_new, g1x = Wg1x*h0_new
        u = ga;
#pragma unroll
        for (int r = 0; r < 4; ++r) gx[r] = ra[r] + bgv[r];
        ZACC;
        MM2(l1h);  // stage 1 on h1(t-2)
        ksum = ZERO4;
        GATEALL(1.0f, 0.5f, bufA);
      }
    }
    __syncthreads();

    // ===== slot B: stage 2 =====
    if ((isL0 && i < NSTEP) || (!isL0 && i >= 1)) {
      ZACC;
      MM2(bufA);
      GATEALL(2.0f, 0.5f, bufB);
    }
    __syncthreads();

    // ===== slot C: stage 3 =====
    if ((isL0 && i < NSTEP) || (!isL0 && i >= 1)) {
      ZACC;
      MM2(bufB);
      GATEALL(2.0f, 1.0f, bufA);
    }
    __syncthreads();

    // ===== slot D: stage 4 -> h_new; L0 stages x(i+1) =====
    if (isL0) {
      if (i < NSTEP) {
        ZACC;
        MM2(bufA);
        GATEFIN((i & 1) ? hq1 : hq0);
        if (tid < 256 && i + 1 < NSTEP)
          *(f16x4*)(xt + bs * 72 + 4 * fp) =
              (f16x4){(f16)sqv.x, (f16)sqv.y, (f16)sqv.z, (f16)sqv.w};
      }
    } else {
      if (i >= 1) {
        ZACC;
        MM2(bufA);
        GATEFIN(l1h);
      }
    }
    __syncthreads();
  }

  // ======================= classifier epilogue ===========================
  float* h1f = (float*)smem;  // [16][132] f32
  if (!isL0) *(f32x4*)(h1f + c * 132 + jb) = hst;
  __syncthreads();
  float* z1 = (float*)(smem + 16 * 132 * 4);  // [16][64] f32
  {
    int b = tid >> 6, o = tid & 63;  // 16 x 64 = 1024 threads exactly
    const float* wr = W1 + o * 128;
    const float* hr = h1f + b * 132;
    float s = 0.f;
#pragma unroll
    for (int j = 0; j < 128; j += 4) {
      f32x4 wv = *(const f32x4*)(wr + j);
      f32x4 hv = *(const f32x4*)(hr + j);
      s += wv[0] * hv[0] + wv[1] * hv[1] + wv[2] * hv[2] + wv[3] * hv[3];
    }
    s += b1[o];
    z1[b * 64 + o] = fmaxf(s, 0.f);
  }
  __syncthreads();
  if (tid < 16) {
    float s = b2[0];
#pragma unroll
    for (int o = 0; o < 64; ++o) s += z1[tid * 64 + o] * W2[o];
    out[bg * 16 + tid] = rcp_f(1.f + __expf(-s));
  }
}

extern "C" void kernel_launch(void* const* d_in, const int* in_sizes, int n_in,
                              void* d_out, int out_size, void* d_ws, size_t ws_size,
                              hipStream_t stream) {
  (void)in_sizes; (void)n_in; (void)out_size; (void)ws_size;
  const float* seq = (const float*)d_in[0];
  const float* ctx = (const float*)d_in[1];
  const float* tau0 = (const float*)d_in[2];
  const float* Win0 = (const float*)d_in[3];
  const float* Wrec0 = (const float*)d_in[4];
  const float* Wg0 = (const float*)d_in[5];
  const float* bg0 = (const float*)d_in[6];
  const float* tau1 = (const float*)d_in[7];
  const float* Win1 = (const float*)d_in[8];
  const float* Wrec1 = (const float*)d_in[9];
  const float* Wg1 = (const float*)d_in[10];
  const float* bg1 = (const float*)d_in[11];
  const float* W1 = (const float*)d_in[12];
  const float* b1 = (const float*)d_in[13];
  const float* W2 = (const float*)d_in[14];
  const float* b2 = (const float*)d_in[15];
  f16* W = (f16*)d_ws;  // 245760 B of packed fragments

  prep_kernel<<<480, 256, 0, stream>>>(Win0, Wrec0, Wg0, Win1, Wrec1, Wg1, W);
  ltc_kernel<<<32, 1024, 0, stream>>>(seq, ctx, tau0, bg0, tau1, bg1, W1, b1, W2,
                                      b2, W, (float*)d_out);
}